// Round 11
// baseline (149.528 us; speedup 1.0000x reference)
//
#include <hip/hip_runtime.h>

// ws >= 22 MiB. Layout: xb@0 4M | wqt@4M .5M | wkt@4.5M .5M | wvt@5M .5M |
// wpt@5.5M .5M | Qb@6M 4M | Kb@10M 4M | Vtb@14M 4M | yb@18M 4M

typedef unsigned short u16;
typedef unsigned int   u32;
typedef __bf16 bf16x8 __attribute__((ext_vector_type(8)));
typedef float  f32x4  __attribute__((ext_vector_type(4)));
typedef short  s16x4  __attribute__((ext_vector_type(4)));

#define WAITV(n) asm volatile("s_waitcnt vmcnt(" #n ")" ::: "memory")
#define BARRIER() asm volatile("s_barrier" ::: "memory")

static __device__ __forceinline__ u16 f2b(float f) {
  __bf16 h = (__bf16)f;
  return __builtin_bit_cast(u16, h);
}
static __device__ __forceinline__ u32 pack2(float a, float b) {
  return (u32)f2b(a) | ((u32)f2b(b) << 16);
}
static __device__ __forceinline__ bf16x8 ld_bf16x8(const u16* p) {
  uint4 u = *(const uint4*)p;
  return __builtin_bit_cast(bf16x8, u);
}
static __device__ __forceinline__ f32x4 mfma32(bf16x8 a, bf16x8 b, f32x4 c) {
  return __builtin_amdgcn_mfma_f32_16x16x32_bf16(a, b, c, 0, 0, 0);
}
static __device__ __forceinline__ f32x4 mfma16(s16x4 a, s16x4 b, f32x4 c) {
  return __builtin_amdgcn_mfma_f32_16x16x16bf16_1k(a, b, c, 0, 0, 0);
}
// native exp2 (1 instruction; OCML exp2f adds denormal-handling overhead)
static __device__ __forceinline__ float exp2n(float x) {
  float r;
  asm("v_exp_f32 %0, %1" : "=v"(r) : "v"(x));
  return r;
}
// async global->LDS, 16 B per lane; lds dest = wave-uniform base + lane*16
static __device__ __forceinline__ void gload16(const u16* g, u16* l) {
  __builtin_amdgcn_global_load_lds(
      (const __attribute__((address_space(1))) void*)g,
      (__attribute__((address_space(3))) void*)l, 16, 0, 0);
}

// ---------------- convert x: f32 -> bf16, [4096][512] ----------------
__global__ __launch_bounds__(256) void k_cvt_x(const float* __restrict__ x,
                                               u16* __restrict__ xb) {
  int i = blockIdx.x * 256 + threadIdx.x;
  const float4* s = (const float4*)x;
  float4 a = s[2 * i], b = s[2 * i + 1];
  uint4 o;
  o.x = pack2(a.x, a.y);
  o.y = pack2(a.z, a.w);
  o.z = pack2(b.x, b.y);
  o.w = pack2(b.z, b.w);
  ((uint4*)xb)[i] = o;
}

// ------------- convert + transpose weights: Wt[n][k] = W[k][n] -------------
__global__ __launch_bounds__(256) void k_cvt_w(
    const float* __restrict__ Wq, const float* __restrict__ Wk,
    const float* __restrict__ Wv, const float* __restrict__ Wp,
    u16* __restrict__ oq, u16* __restrict__ ok,
    u16* __restrict__ ov, u16* __restrict__ op) {
  const int z = blockIdx.z;
  const float* src = (z == 0) ? Wq : (z == 1) ? Wk : (z == 2) ? Wv : Wp;
  u16* dst = (z == 0) ? oq : (z == 1) ? ok : (z == 2) ? ov : op;
  __shared__ float t[32][33];
  const int tx = threadIdx.x, ty = threadIdx.y;  // 32 x 8
  const int n0 = blockIdx.x * 32, k0 = blockIdx.y * 32;
#pragma unroll
  for (int i = 0; i < 4; ++i)
    t[ty + i * 8][tx] = src[(size_t)(k0 + ty + i * 8) * 512 + n0 + tx];
  __syncthreads();
#pragma unroll
  for (int i = 0; i < 4; ++i)
    dst[(size_t)(n0 + ty + i * 8) * 512 + k0 + tx] = f2b(t[tx][ty + i * 8]);
}

// ---------------- GEMM: C[m][n] = (sum_k A[m][k]*Bt[n][k] + bias[n])*scl ---
// 128x64 tile, BK=64, 512 thr (8 waves 4x2, wave tile 32x32, MI=NI=2).
// 3-buffer global_load_lds staging, counted vmcnt + raw s_barrier.
// UNCHANGED from round 10 (isolating attn changes; profile next round).
__global__ __launch_bounds__(512, 4) void k_gemm(
    const u16* __restrict__ A,
    const u16* __restrict__ Bt_0, const u16* __restrict__ Bt_1,
    const u16* __restrict__ Bt_2,
    const float* __restrict__ bias_0, const float* __restrict__ bias_1,
    const float* __restrict__ bias_2,
    float scl_0, float scl_1, float scl_2,
    void* out_0, void* out_1, void* out_2,
    int mode_0, int mode_1, int mode_2) {
  const int z = blockIdx.z;
  const u16* Bt = (z == 0) ? Bt_0 : (z == 1) ? Bt_1 : Bt_2;
  const float* bias = (z == 0) ? bias_0 : (z == 1) ? bias_1 : bias_2;
  const float scl = (z == 0) ? scl_0 : (z == 1) ? scl_1 : scl_2;
  void* outp = (z == 0) ? out_0 : (z == 1) ? out_1 : out_2;
  const int mode = (z == 0) ? mode_0 : (z == 1) ? mode_1 : mode_2;

  const int tid = threadIdx.x, lane = tid & 63, w = tid >> 6;
  const int wm = w >> 1, wn = w & 1;  // 4 x 2 wave grid
  const int lr = lane & 15, lg = lane >> 4;
  const int m0 = blockIdx.y * 128, n0 = blockIdx.x * 64;

  __shared__ __align__(16) u16 As[3][128 * 64];
  __shared__ __align__(16) u16 Bs[3][64 * 64];

  f32x4 acc[2][2];
  const f32x4 fz = {0.f, 0.f, 0.f, 0.f};
#pragma unroll
  for (int mi = 0; mi < 2; ++mi)
#pragma unroll
    for (int ni = 0; ni < 2; ++ni) acc[mi][ni] = fz;

  const int lro = lane >> 3;
  const int lch = (lane & 7) ^ (lro & 7);

  auto stage = [&](int kk, int buf) {
#pragma unroll
    for (int j = 0; j < 2; ++j) {
      const int r0 = w * 16 + j * 8;
      gload16(A + (size_t)(m0 + r0 + lro) * 512 + kk + lch * 8,
              &As[buf][r0 * 64]);
    }
    {
      const int r0 = w * 8;
      gload16(Bt + (size_t)(n0 + r0 + lro) * 512 + kk + lch * 8,
              &Bs[buf][r0 * 64]);
    }
  };

  // loop-invariant read offsets: chunk (kc*4+lg) ^ (lr&7), r&7 == lr&7
  const int e0 = ((lg ^ (lr & 7)) << 3);
  const int e1 = (((4 + lg) ^ (lr & 7)) << 3);
  const int arow = wm * 32 + lr;  // + mi*16 folds to imm
  const int brow = wn * 32 + lr;

  stage(0, 0);
  stage(64, 1);
  int cur = 0, nx2 = 2;
  for (int kt = 0; kt < 8; ++kt) {
    if (kt < 7) WAITV(3); else WAITV(0);
    BARRIER();
    if (kt + 2 < 8) stage((kt + 2) * 64, nx2);

#pragma unroll
    for (int kc = 0; kc < 2; ++kc) {
      const int e = (kc == 0) ? e0 : e1;
      const u16* Ap = &As[cur][arow * 64 + e];
      const u16* Bp = &Bs[cur][brow * 64 + e];
      bf16x8 af[2], bfv[2];
#pragma unroll
      for (int mi = 0; mi < 2; ++mi) af[mi] = ld_bf16x8(Ap + mi * 1024);
#pragma unroll
      for (int ni = 0; ni < 2; ++ni) bfv[ni] = ld_bf16x8(Bp + ni * 1024);
#pragma unroll
      for (int mi = 0; mi < 2; ++mi)
#pragma unroll
        for (int ni = 0; ni < 2; ++ni)
          acc[mi][ni] = mfma32(af[mi], bfv[ni], acc[mi][ni]);
    }
    cur = (cur == 2) ? 0 : cur + 1;
    nx2 = (nx2 == 2) ? 0 : nx2 + 1;
  }

  // epilogue: D-frag mapping col = lane&15 (n), row = (lane>>4)*4+i (m)
#pragma unroll
  for (int mi = 0; mi < 2; ++mi) {
#pragma unroll
    for (int ni = 0; ni < 2; ++ni) {
      const int mbase = m0 + wm * 32 + mi * 16 + lg * 4;
      const int n = n0 + wn * 32 + ni * 16 + lr;
      const float bsv = bias[n];
      if (mode == 0) {
        u16* o = (u16*)outp;
#pragma unroll
        for (int i = 0; i < 4; ++i)
          o[(size_t)(mbase + i) * 512 + n] = f2b((acc[mi][ni][i] + bsv) * scl);
      } else if (mode == 1) {
        // Vt[((b*8+h)*64+d)][t],  b=m>>11, t=m&2047, h=n>>6, d=n&63
        u16* o = (u16*)outp;
        const int bb = mbase >> 11, t = mbase & 2047;
        const size_t rowb = ((size_t)(bb * 8 + (n >> 6)) * 64 + (n & 63)) * 2048;
        *(u32*)(o + rowb + t)     = pack2(acc[mi][ni][0] + bsv, acc[mi][ni][1] + bsv);
        *(u32*)(o + rowb + t + 2) = pack2(acc[mi][ni][2] + bsv, acc[mi][ni][3] + bsv);
      } else {
        float* o = (float*)outp;
#pragma unroll
        for (int i = 0; i < 4; ++i)
          o[(size_t)(mbase + i) * 512 + n] = acc[mi][ni][i] + bsv;
      }
    }
  }
}

// ---- attention: flash-style, 4-buffer depth-3 LDS K/V pipeline -------------
// Block = 256 thr (4 waves) = one 64-row q-tile; qt = 31 - blockIdx.x (LPT).
// vmcnt ledger (4 loads/stage): steady 12 outstanding; WAITV(8) drains
// exactly stage(c); tail WAITV(4)/WAITV(0). Mask preloaded as bias in LDS
// + per-chunk clean flags (all-ones chunk skips bias path entirely).
__global__ __launch_bounds__(256, 2) void k_attn(
    const u16* __restrict__ Q, const u16* __restrict__ K,
    const u16* __restrict__ Vt, const int* __restrict__ mask,
    u16* __restrict__ y) {
  const int b = blockIdx.z, h = blockIdx.y;
  const int qt = 31 - blockIdx.x;  // heavy tiles dispatched first
  const int tid = threadIdx.x, lane = tid & 63, w = tid >> 6;
  const int lr = lane & 15, lg = lane >> 4;
  const int q0 = qt * 64 + w * 16;
  const int fq = (q0 + lr) >> 2;  // query frame (per lane)
  const float NINF = -__builtin_inff();

  __shared__ __align__(16) u16 Ks[4][64 * 64];
  __shared__ __align__(16) u16 Vs[4][64 * 64];
  __shared__ __align__(16) float mb[2048];
  __shared__ int mflag[32];

  // ---- mask -> float bias (0 / -inf) + per-chunk dirty flags ----
  if (tid < 32) mflag[tid] = 0;
  __syncthreads();
  {
    const int4* m4 = (const int4*)(mask + b * 2048);
    int4 a = m4[tid * 2], c = m4[tid * 2 + 1];
    float* d = &mb[tid * 8];
    d[0] = a.x ? 0.f : NINF; d[1] = a.y ? 0.f : NINF;
    d[2] = a.z ? 0.f : NINF; d[3] = a.w ? 0.f : NINF;
    d[4] = c.x ? 0.f : NINF; d[5] = c.y ? 0.f : NINF;
    d[6] = c.z ? 0.f : NINF; d[7] = c.w ? 0.f : NINF;
    if ((a.x & a.y & a.z & a.w & c.x & c.y & c.z & c.w) == 0)
      atomicOr(&mflag[tid >> 3], 1);
  }
  __syncthreads();  // before any async staging; drains mb/mflag writes

  const size_t brow = (size_t)b * 2048;
  const u16* qp = Q + (brow + q0 + lr) * 512 + h * 64 + lg * 8;
  const bf16x8 qf0 = ld_bf16x8(qp);
  const bf16x8 qf1 = ld_bf16x8(qp + 32);

  const f32x4 fz = {0.f, 0.f, 0.f, 0.f};
  f32x4 yacc[4];
#pragma unroll
  for (int dt = 0; dt < 4; ++dt) yacc[dt] = fz;
  float mrun = -1.0e4f, lpart = 0.f;

  const int lro = lane >> 3;
  const int lch = (lane & 7) ^ (lro & 7);
  const u16* kgbase = K + brow * 512 + h * 64 + lch * 8;
  const u16* vgbase = Vt + ((size_t)(b * 8 + h) * 64) * 2048 + lch * 8;

  auto stage = [&](int c, int buf) {
    const int c0 = c << 6;
#pragma unroll
    for (int j = 0; j < 2; ++j) {
      const int r0 = w * 16 + j * 8;
      gload16(kgbase + (size_t)(c0 + r0 + lro) * 512, &Ks[buf][r0 * 64]);
    }
#pragma unroll
    for (int j = 0; j < 2; ++j) {
      const int r0 = w * 16 + j * 8;
      gload16(vgbase + (size_t)(r0 + lro) * 2048 + c0, &Vs[buf][r0 * 64]);
    }
  };

  // ---- loop-invariant LDS read offsets (u16 elems) ----
  const int kb0 = lr * 64 + ((lg ^ (lr & 7)) << 3);
  const int kb1 = lr * 64 + (((4 + lg) ^ (lr & 7)) << 3);
  const int vf = (lg >> 1) ^ (lr & 7);
  int vh[4];
#pragma unroll
  for (int kt = 0; kt < 4; ++kt)
    vh[kt] = lr * 64 + (((2 * kt) ^ vf) << 3) + ((lg & 1) << 2);

  auto step = [&](int c, int buf, bool diag) {
    const u16* kp = &Ks[buf][0];
    const u16* vp = &Vs[buf][0];

    // QK^T: 8 MFMAs, 4 independent chains of 2 (log2-domain scores)
    f32x4 s[4];
#pragma unroll
    for (int kt = 0; kt < 4; ++kt)
      s[kt] = mfma32(ld_bf16x8(kp + kb0 + kt * 1024), qf0, fz);
#pragma unroll
    for (int kt = 0; kt < 4; ++kt)
      s[kt] = mfma32(ld_bf16x8(kp + kb1 + kt * 1024), qf1, s[kt]);

    // bias only when chunk has masked keys; causal only on diagonal chunk
    float sv[4][4];
    float tm = NINF;
    const bool dirty = mflag[c] != 0;
    if (dirty || diag) {
      const float* mbp = &mb[c * 64 + lg * 4];
#pragma unroll
      for (int kt = 0; kt < 4; ++kt) {
        float4 mv = {0.f, 0.f, 0.f, 0.f};
        if (dirty) mv = *(const float4*)(mbp + kt * 16);
        float kv = 0.f;
        if (diag) kv = ((qt * 16 + kt * 4 + lg) > fq) ? NINF : 0.f;
#pragma unroll
        for (int i = 0; i < 4; ++i) {
          const float bi = (i == 0) ? mv.x : (i == 1) ? mv.y : (i == 2) ? mv.z : mv.w;
          sv[kt][i] = s[kt][i] + bi + kv;
          tm = fmaxf(tm, sv[kt][i]);
        }
      }
    } else {
#pragma unroll
      for (int kt = 0; kt < 4; ++kt)
#pragma unroll
        for (int i = 0; i < 4; ++i) {
          sv[kt][i] = s[kt][i];
          tm = fmaxf(tm, sv[kt][i]);
        }
    }

    // defer-max: rescale only when some lane's max grew past mrun+8
    if (__any(tm > mrun + 8.f)) {
      float tmr = fmaxf(tm, __shfl_xor(tm, 16));
      tmr = fmaxf(tmr, __shfl_xor(tmr, 32));
      const float mnew = fmaxf(mrun, tmr);
      const float alpha = exp2n(mrun - mnew);
      lpart *= alpha;
#pragma unroll
      for (int dt = 0; dt < 4; ++dt)
#pragma unroll
        for (int i = 0; i < 4; ++i) yacc[dt][i] *= alpha;
      mrun = mnew;
    }

    // p = exp2(sv - mrun); per-lane partial sum; pack bf16
    s16x4 pf[4];
#pragma unroll
    for (int kt = 0; kt < 4; ++kt) {
#pragma unroll
      for (int i = 0; i < 4; ++i) {
        const float pv = exp2n(sv[kt][i] - mrun);
        lpart += pv;
        pf[kt][i] = (short)f2b(pv);
      }
    }

    // PV: 16 MFMAs, 4 independent chains (one per dt)
#pragma unroll
    for (int dt = 0; dt < 4; ++dt) {
#pragma unroll
      for (int kt = 0; kt < 4; ++kt) {
        const uint2 vv = *(const uint2*)(vp + vh[kt] + dt * 1024);
        yacc[dt] = mfma16(__builtin_bit_cast(s16x4, vv), pf[kt], yacc[dt]);
      }
    }
  };

  // ---- depth-3 pipeline: stage 0..2, steady WAITV(8) ----
  const int last = qt;
  stage(0, 0);
  if (last >= 1) stage(1, 1);
  if (last >= 2) stage(2, 2);
  for (int c = 0; c < last; ++c) {
    if (c < last - 1) WAITV(8); else WAITV(4);
    BARRIER();
    if (c + 3 <= last) stage(c + 3, (c + 3) & 3);
    step(c, c & 3, false);
  }
  WAITV(0);
  BARRIER();
  step(last, last & 3, true);  // diagonal chunk

  // row-reduce the per-lane partial denominators (once)
  float lsum = lpart + __shfl_xor(lpart, 16);
  lsum += __shfl_xor(lsum, 32);
  const float inv = 1.f / lsum;
#pragma unroll
  for (int dt = 0; dt < 4; ++dt) {
    u32* p2 = (u32*)(y + (brow + q0 + lr) * 512 + h * 64 + dt * 16 + lg * 4);
    p2[0] = pack2(yacc[dt][0] * inv, yacc[dt][1] * inv);
    p2[1] = pack2(yacc[dt][2] * inv, yacc[dt][3] * inv);
  }
}

extern "C" void kernel_launch(void* const* d_in, const int* in_sizes, int n_in,
                              void* d_out, int out_size, void* d_ws,
                              size_t ws_size, hipStream_t stream) {
  const float* x  = (const float*)d_in[0];
  const int* mask = (const int*)d_in[1];
  const float* Wq = (const float*)d_in[2];
  const float* bq = (const float*)d_in[3];
  const float* Wk = (const float*)d_in[4];
  const float* bk = (const float*)d_in[5];
  const float* Wv = (const float*)d_in[6];
  const float* bv = (const float*)d_in[7];
  const float* Wp = (const float*)d_in[8];
  const float* bp = (const float*)d_in[9];

  char* ws = (char*)d_ws;
  u16* xb  = (u16*)(ws);
  u16* wqt = (u16*)(ws + (4u << 20));
  u16* wkt = (u16*)(ws + (4u << 20) + 524288u);
  u16* wvt = (u16*)(ws + (5u << 20));
  u16* wpt = (u16*)(ws + (5u << 20) + 524288u);
  u16* Qb  = (u16*)(ws + (6u << 20));
  u16* Kb  = (u16*)(ws + (10u << 20));
  u16* Vtb = (u16*)(ws + (14u << 20));
  u16* yb  = (u16*)(ws + (18u << 20));

  // 0.125 (1/sqrt(64)) * log2(e): QK scores come out in log2 domain
  const float SCLQ = 0.125f * 1.4426950408889634f;

  k_cvt_x<<<dim3(1024), dim3(256), 0, stream>>>(x, xb);
  k_cvt_w<<<dim3(16, 16, 4), dim3(32, 8), 0, stream>>>(Wq, Wk, Wv, Wp, wqt, wkt,
                                                       wvt, wpt);
  k_gemm<<<dim3(8, 32, 3), dim3(512), 0, stream>>>(
      xb, wqt, wkt, wvt, bq, bk, bv, SCLQ, 1.f, 1.f,
      (void*)Qb, (void*)Kb, (void*)Vtb, 0, 0, 1);
  k_attn<<<dim3(32, 8, 2), dim3(256), 0, stream>>>(Qb, Kb, Vtb, mask, yb);
  k_gemm<<<dim3(8, 32, 1), dim3(512), 0, stream>>>(
      yb, wpt, wpt, wpt, bp, bp, bp, 1.f, 1.f, 1.f,
      d_out, d_out, d_out, 2, 2, 2);
}

// Round 12
// 146.218 us; speedup vs baseline: 1.0226x; 1.0226x over previous
//
#include <hip/hip_runtime.h>

// ws >= 22 MiB. Layout: xb@0 4M | wqt@4M .5M | wkt@4.5M .5M | wvt@5M .5M |
// wpt@5.5M .5M | Qb@6M 4M | Kb@10M 4M | Vtb@14M 4M | yb@18M 4M

typedef unsigned short u16;
typedef unsigned int   u32;
typedef __bf16 bf16x8 __attribute__((ext_vector_type(8)));
typedef float  f32x4  __attribute__((ext_vector_type(4)));
typedef short  s16x4  __attribute__((ext_vector_type(4)));

#define WAITV(n) asm volatile("s_waitcnt vmcnt(" #n ")" ::: "memory")
#define BARRIER() asm volatile("s_barrier" ::: "memory")

static __device__ __forceinline__ u16 f2b(float f) {
  __bf16 h = (__bf16)f;
  return __builtin_bit_cast(u16, h);
}
static __device__ __forceinline__ u32 pack2(float a, float b) {
  return (u32)f2b(a) | ((u32)f2b(b) << 16);
}
static __device__ __forceinline__ bf16x8 ld_bf16x8(const u16* p) {
  uint4 u = *(const uint4*)p;
  return __builtin_bit_cast(bf16x8, u);
}
static __device__ __forceinline__ f32x4 mfma32(bf16x8 a, bf16x8 b, f32x4 c) {
  return __builtin_amdgcn_mfma_f32_16x16x32_bf16(a, b, c, 0, 0, 0);
}
static __device__ __forceinline__ f32x4 mfma16(s16x4 a, s16x4 b, f32x4 c) {
  return __builtin_amdgcn_mfma_f32_16x16x16bf16_1k(a, b, c, 0, 0, 0);
}
// native exp2 (1 instruction; OCML exp2f adds denormal-handling overhead)
static __device__ __forceinline__ float exp2n(float x) {
  float r;
  asm("v_exp_f32 %0, %1" : "=v"(r) : "v"(x));
  return r;
}
// async global->LDS, 16 B per lane; lds dest = wave-uniform base + lane*16
static __device__ __forceinline__ void gload16(const u16* g, u16* l) {
  __builtin_amdgcn_global_load_lds(
      (const __attribute__((address_space(1))) void*)g,
      (__attribute__((address_space(3))) void*)l, 16, 0, 0);
}

// ---------------- convert x: f32 -> bf16, [4096][512] ----------------
__global__ __launch_bounds__(256) void k_cvt_x(const float* __restrict__ x,
                                               u16* __restrict__ xb) {
  int i = blockIdx.x * 256 + threadIdx.x;
  const float4* s = (const float4*)x;
  float4 a = s[2 * i], b = s[2 * i + 1];
  uint4 o;
  o.x = pack2(a.x, a.y);
  o.y = pack2(a.z, a.w);
  o.z = pack2(b.x, b.y);
  o.w = pack2(b.z, b.w);
  ((uint4*)xb)[i] = o;
}

// ------------- convert + transpose weights: Wt[n][k] = W[k][n] -------------
__global__ __launch_bounds__(256) void k_cvt_w(
    const float* __restrict__ Wq, const float* __restrict__ Wk,
    const float* __restrict__ Wv, const float* __restrict__ Wp,
    u16* __restrict__ oq, u16* __restrict__ ok,
    u16* __restrict__ ov, u16* __restrict__ op) {
  const int z = blockIdx.z;
  const float* src = (z == 0) ? Wq : (z == 1) ? Wk : (z == 2) ? Wv : Wp;
  u16* dst = (z == 0) ? oq : (z == 1) ? ok : (z == 2) ? ov : op;
  __shared__ float t[32][33];
  const int tx = threadIdx.x, ty = threadIdx.y;  // 32 x 8
  const int n0 = blockIdx.x * 32, k0 = blockIdx.y * 32;
#pragma unroll
  for (int i = 0; i < 4; ++i)
    t[ty + i * 8][tx] = src[(size_t)(k0 + ty + i * 8) * 512 + n0 + tx];
  __syncthreads();
#pragma unroll
  for (int i = 0; i < 4; ++i)
    dst[(size_t)(n0 + ty + i * 8) * 512 + k0 + tx] = f2b(t[tx][ty + i * 8]);
}

// ---------------- GEMM: C[m][n] = (sum_k A[m][k]*Bt[n][k] + bias[n])*scl ---
// 128x64 tile, BK=64, 512 thr (8 waves 4x2, wave tile 32x32, MI=NI=2).
// 3-buffer global_load_lds staging, counted vmcnt + raw s_barrier.
// BYTE-IDENTICAL to round 10/11 (awaiting counters before touching).
__global__ __launch_bounds__(512, 4) void k_gemm(
    const u16* __restrict__ A,
    const u16* __restrict__ Bt_0, const u16* __restrict__ Bt_1,
    const u16* __restrict__ Bt_2,
    const float* __restrict__ bias_0, const float* __restrict__ bias_1,
    const float* __restrict__ bias_2,
    float scl_0, float scl_1, float scl_2,
    void* out_0, void* out_1, void* out_2,
    int mode_0, int mode_1, int mode_2) {
  const int z = blockIdx.z;
  const u16* Bt = (z == 0) ? Bt_0 : (z == 1) ? Bt_1 : Bt_2;
  const float* bias = (z == 0) ? bias_0 : (z == 1) ? bias_1 : bias_2;
  const float scl = (z == 0) ? scl_0 : (z == 1) ? scl_1 : scl_2;
  void* outp = (z == 0) ? out_0 : (z == 1) ? out_1 : out_2;
  const int mode = (z == 0) ? mode_0 : (z == 1) ? mode_1 : mode_2;

  const int tid = threadIdx.x, lane = tid & 63, w = tid >> 6;
  const int wm = w >> 1, wn = w & 1;  // 4 x 2 wave grid
  const int lr = lane & 15, lg = lane >> 4;
  const int m0 = blockIdx.y * 128, n0 = blockIdx.x * 64;

  __shared__ __align__(16) u16 As[3][128 * 64];
  __shared__ __align__(16) u16 Bs[3][64 * 64];

  f32x4 acc[2][2];
  const f32x4 fz = {0.f, 0.f, 0.f, 0.f};
#pragma unroll
  for (int mi = 0; mi < 2; ++mi)
#pragma unroll
    for (int ni = 0; ni < 2; ++ni) acc[mi][ni] = fz;

  const int lro = lane >> 3;
  const int lch = (lane & 7) ^ (lro & 7);

  auto stage = [&](int kk, int buf) {
#pragma unroll
    for (int j = 0; j < 2; ++j) {
      const int r0 = w * 16 + j * 8;
      gload16(A + (size_t)(m0 + r0 + lro) * 512 + kk + lch * 8,
              &As[buf][r0 * 64]);
    }
    {
      const int r0 = w * 8;
      gload16(Bt + (size_t)(n0 + r0 + lro) * 512 + kk + lch * 8,
              &Bs[buf][r0 * 64]);
    }
  };

  // loop-invariant read offsets: chunk (kc*4+lg) ^ (lr&7), r&7 == lr&7
  const int e0 = ((lg ^ (lr & 7)) << 3);
  const int e1 = (((4 + lg) ^ (lr & 7)) << 3);
  const int arow = wm * 32 + lr;  // + mi*16 folds to imm
  const int brow = wn * 32 + lr;

  stage(0, 0);
  stage(64, 1);
  int cur = 0, nx2 = 2;
  for (int kt = 0; kt < 8; ++kt) {
    if (kt < 7) WAITV(3); else WAITV(0);
    BARRIER();
    if (kt + 2 < 8) stage((kt + 2) * 64, nx2);

#pragma unroll
    for (int kc = 0; kc < 2; ++kc) {
      const int e = (kc == 0) ? e0 : e1;
      const u16* Ap = &As[cur][arow * 64 + e];
      const u16* Bp = &Bs[cur][brow * 64 + e];
      bf16x8 af[2], bfv[2];
#pragma unroll
      for (int mi = 0; mi < 2; ++mi) af[mi] = ld_bf16x8(Ap + mi * 1024);
#pragma unroll
      for (int ni = 0; ni < 2; ++ni) bfv[ni] = ld_bf16x8(Bp + ni * 1024);
#pragma unroll
      for (int mi = 0; mi < 2; ++mi)
#pragma unroll
        for (int ni = 0; ni < 2; ++ni)
          acc[mi][ni] = mfma32(af[mi], bfv[ni], acc[mi][ni]);
    }
    cur = (cur == 2) ? 0 : cur + 1;
    nx2 = (nx2 == 2) ? 0 : nx2 + 1;
  }

  // epilogue: D-frag mapping col = lane&15 (n), row = (lane>>4)*4+i (m)
#pragma unroll
  for (int mi = 0; mi < 2; ++mi) {
#pragma unroll
    for (int ni = 0; ni < 2; ++ni) {
      const int mbase = m0 + wm * 32 + mi * 16 + lg * 4;
      const int n = n0 + wn * 32 + ni * 16 + lr;
      const float bsv = bias[n];
      if (mode == 0) {
        u16* o = (u16*)outp;
#pragma unroll
        for (int i = 0; i < 4; ++i)
          o[(size_t)(mbase + i) * 512 + n] = f2b((acc[mi][ni][i] + bsv) * scl);
      } else if (mode == 1) {
        // Vt[((b*8+h)*64+d)][t],  b=m>>11, t=m&2047, h=n>>6, d=n&63
        u16* o = (u16*)outp;
        const int bb = mbase >> 11, t = mbase & 2047;
        const size_t rowb = ((size_t)(bb * 8 + (n >> 6)) * 64 + (n & 63)) * 2048;
        *(u32*)(o + rowb + t)     = pack2(acc[mi][ni][0] + bsv, acc[mi][ni][1] + bsv);
        *(u32*)(o + rowb + t + 2) = pack2(acc[mi][ni][2] + bsv, acc[mi][ni][3] + bsv);
      } else {
        float* o = (float*)outp;
#pragma unroll
        for (int i = 0; i < 4; ++i)
          o[(size_t)(mbase + i) * 512 + n] = acc[mi][ni][i] + bsv;
      }
    }
  }
}

// ---- attention: flash-style, 4-buffer depth-3 LDS K/V pipeline -------------
// Block = 256 thr (4 waves) = one 64-row q-tile.
// COMPLEMENTARY PAIRING: qt = (b==1) ? bx : 31-bx, so blocks L and L+256
// (co-resident on one CU when 512 blocks fill 256 CUs twice) have qt summing
// to 31 -> every CU executes exactly 33 chunk-steps (balanced makespan).
__global__ __launch_bounds__(256, 2) void k_attn(
    const u16* __restrict__ Q, const u16* __restrict__ K,
    const u16* __restrict__ Vt, const int* __restrict__ mask,
    u16* __restrict__ y) {
  const int b = blockIdx.z, h = blockIdx.y;
  const int qt = b ? blockIdx.x : (31 - blockIdx.x);  // complementary pairing
  const int tid = threadIdx.x, lane = tid & 63, w = tid >> 6;
  const int lr = lane & 15, lg = lane >> 4;
  const int q0 = qt * 64 + w * 16;
  const int fq = (q0 + lr) >> 2;  // query frame (per lane)
  const float NINF = -__builtin_inff();

  __shared__ __align__(16) u16 Ks[4][64 * 64];
  __shared__ __align__(16) u16 Vs[4][64 * 64];
  __shared__ __align__(16) float mb[2048];
  __shared__ int mflag[32];

  // ---- mask -> float bias (0 / -inf) + per-chunk dirty flags ----
  if (tid < 32) mflag[tid] = 0;
  __syncthreads();
  {
    const int4* m4 = (const int4*)(mask + b * 2048);
    int4 a = m4[tid * 2], c = m4[tid * 2 + 1];
    float* d = &mb[tid * 8];
    d[0] = a.x ? 0.f : NINF; d[1] = a.y ? 0.f : NINF;
    d[2] = a.z ? 0.f : NINF; d[3] = a.w ? 0.f : NINF;
    d[4] = c.x ? 0.f : NINF; d[5] = c.y ? 0.f : NINF;
    d[6] = c.z ? 0.f : NINF; d[7] = c.w ? 0.f : NINF;
    if ((a.x & a.y & a.z & a.w & c.x & c.y & c.z & c.w) == 0)
      atomicOr(&mflag[tid >> 3], 1);
  }
  __syncthreads();  // before any async staging; drains mb/mflag writes

  const size_t brow = (size_t)b * 2048;
  const u16* qp = Q + (brow + q0 + lr) * 512 + h * 64 + lg * 8;
  const bf16x8 qf0 = ld_bf16x8(qp);
  const bf16x8 qf1 = ld_bf16x8(qp + 32);

  const f32x4 fz = {0.f, 0.f, 0.f, 0.f};
  f32x4 yacc[4];
#pragma unroll
  for (int dt = 0; dt < 4; ++dt) yacc[dt] = fz;
  float mrun = -1.0e4f, lpart = 0.f;

  const int lro = lane >> 3;
  const int lch = (lane & 7) ^ (lro & 7);
  const u16* kgbase = K + brow * 512 + h * 64 + lch * 8;
  const u16* vgbase = Vt + ((size_t)(b * 8 + h) * 64) * 2048 + lch * 8;

  auto stage = [&](int c, int buf) {
    const int c0 = c << 6;
#pragma unroll
    for (int j = 0; j < 2; ++j) {
      const int r0 = w * 16 + j * 8;
      gload16(kgbase + (size_t)(c0 + r0 + lro) * 512, &Ks[buf][r0 * 64]);
    }
#pragma unroll
    for (int j = 0; j < 2; ++j) {
      const int r0 = w * 16 + j * 8;
      gload16(vgbase + (size_t)(r0 + lro) * 2048 + c0, &Vs[buf][r0 * 64]);
    }
  };

  // ---- loop-invariant LDS read offsets (u16 elems) ----
  const int kb0 = lr * 64 + ((lg ^ (lr & 7)) << 3);
  const int kb1 = lr * 64 + (((4 + lg) ^ (lr & 7)) << 3);
  const int vf = (lg >> 1) ^ (lr & 7);
  int vh[4];
#pragma unroll
  for (int kt = 0; kt < 4; ++kt)
    vh[kt] = lr * 64 + (((2 * kt) ^ vf) << 3) + ((lg & 1) << 2);

  auto step = [&](int c, int buf, bool diag) {
    const u16* kp = &Ks[buf][0];
    const u16* vp = &Vs[buf][0];

    // QK^T: 8 MFMAs, 4 independent chains of 2 (log2-domain scores)
    f32x4 s[4];
#pragma unroll
    for (int kt = 0; kt < 4; ++kt)
      s[kt] = mfma32(ld_bf16x8(kp + kb0 + kt * 1024), qf0, fz);
#pragma unroll
    for (int kt = 0; kt < 4; ++kt)
      s[kt] = mfma32(ld_bf16x8(kp + kb1 + kt * 1024), qf1, s[kt]);

    // bias only when chunk has masked keys; causal only on diagonal chunk
    float sv[4][4];
    float tm = NINF;
    const bool dirty = mflag[c] != 0;
    if (dirty || diag) {
      const float* mbp = &mb[c * 64 + lg * 4];
#pragma unroll
      for (int kt = 0; kt < 4; ++kt) {
        float4 mv = {0.f, 0.f, 0.f, 0.f};
        if (dirty) mv = *(const float4*)(mbp + kt * 16);
        float kv = 0.f;
        if (diag) kv = ((qt * 16 + kt * 4 + lg) > fq) ? NINF : 0.f;
#pragma unroll
        for (int i = 0; i < 4; ++i) {
          const float bi = (i == 0) ? mv.x : (i == 1) ? mv.y : (i == 2) ? mv.z : mv.w;
          sv[kt][i] = s[kt][i] + bi + kv;
          tm = fmaxf(tm, sv[kt][i]);
        }
      }
    } else {
#pragma unroll
      for (int kt = 0; kt < 4; ++kt)
#pragma unroll
        for (int i = 0; i < 4; ++i) {
          sv[kt][i] = s[kt][i];
          tm = fmaxf(tm, sv[kt][i]);
        }
    }

    // defer-max: rescale only when some lane's max grew past mrun+8
    if (__any(tm > mrun + 8.f)) {
      float tmr = fmaxf(tm, __shfl_xor(tm, 16));
      tmr = fmaxf(tmr, __shfl_xor(tmr, 32));
      const float mnew = fmaxf(mrun, tmr);
      const float alpha = exp2n(mrun - mnew);
      lpart *= alpha;
#pragma unroll
      for (int dt = 0; dt < 4; ++dt)
#pragma unroll
        for (int i = 0; i < 4; ++i) yacc[dt][i] *= alpha;
      mrun = mnew;
    }

    // p = exp2(sv - mrun); per-lane partial sum; pack bf16
    s16x4 pf[4];
#pragma unroll
    for (int kt = 0; kt < 4; ++kt) {
#pragma unroll
      for (int i = 0; i < 4; ++i) {
        const float pv = exp2n(sv[kt][i] - mrun);
        lpart += pv;
        pf[kt][i] = (short)f2b(pv);
      }
    }

    // PV: 16 MFMAs, 4 independent chains (one per dt)
#pragma unroll
    for (int dt = 0; dt < 4; ++dt) {
#pragma unroll
      for (int kt = 0; kt < 4; ++kt) {
        const uint2 vv = *(const uint2*)(vp + vh[kt] + dt * 1024);
        yacc[dt] = mfma16(__builtin_bit_cast(s16x4, vv), pf[kt], yacc[dt]);
      }
    }
  };

  // ---- depth-3 pipeline: stage 0..2, steady WAITV(8) ----
  const int last = qt;
  stage(0, 0);
  if (last >= 1) stage(1, 1);
  if (last >= 2) stage(2, 2);
  for (int c = 0; c < last; ++c) {
    if (c < last - 1) WAITV(8); else WAITV(4);
    BARRIER();
    if (c + 3 <= last) stage(c + 3, (c + 3) & 3);
    step(c, c & 3, false);
  }
  WAITV(0);
  BARRIER();
  step(last, last & 3, true);  // diagonal chunk

  // row-reduce the per-lane partial denominators (once)
  float lsum = lpart + __shfl_xor(lpart, 16);
  lsum += __shfl_xor(lsum, 32);
  const float inv = 1.f / lsum;
#pragma unroll
  for (int dt = 0; dt < 4; ++dt) {
    u32* p2 = (u32*)(y + (brow + q0 + lr) * 512 + h * 64 + dt * 16 + lg * 4);
    p2[0] = pack2(yacc[dt][0] * inv, yacc[dt][1] * inv);
    p2[1] = pack2(yacc[dt][2] * inv, yacc[dt][3] * inv);
  }
}

extern "C" void kernel_launch(void* const* d_in, const int* in_sizes, int n_in,
                              void* d_out, int out_size, void* d_ws,
                              size_t ws_size, hipStream_t stream) {
  const float* x  = (const float*)d_in[0];
  const int* mask = (const int*)d_in[1];
  const float* Wq = (const float*)d_in[2];
  const float* bq = (const float*)d_in[3];
  const float* Wk = (const float*)d_in[4];
  const float* bk = (const float*)d_in[5];
  const float* Wv = (const float*)d_in[6];
  const float* bv = (const float*)d_in[7];
  const float* Wp = (const float*)d_in[8];
  const float* bp = (const float*)d_in[9];

  char* ws = (char*)d_ws;
  u16* xb  = (u16*)(ws);
  u16* wqt = (u16*)(ws + (4u << 20));
  u16* wkt = (u16*)(ws + (4u << 20) + 524288u);
  u16* wvt = (u16*)(ws + (5u << 20));
  u16* wpt = (u16*)(ws + (5u << 20) + 524288u);
  u16* Qb  = (u16*)(ws + (6u << 20));
  u16* Kb  = (u16*)(ws + (10u << 20));
  u16* Vtb = (u16*)(ws + (14u << 20));
  u16* yb  = (u16*)(ws + (18u << 20));

  // 0.125 (1/sqrt(64)) * log2(e): QK scores come out in log2 domain
  const float SCLQ = 0.125f * 1.4426950408889634f;

  k_cvt_x<<<dim3(1024), dim3(256), 0, stream>>>(x, xb);
  k_cvt_w<<<dim3(16, 16, 4), dim3(32, 8), 0, stream>>>(Wq, Wk, Wv, Wp, wqt, wkt,
                                                       wvt, wpt);
  k_gemm<<<dim3(8, 32, 3), dim3(512), 0, stream>>>(
      xb, wqt, wkt, wvt, bq, bk, bv, SCLQ, 1.f, 1.f,
      (void*)Qb, (void*)Kb, (void*)Vtb, 0, 0, 1);
  k_attn<<<dim3(32, 8, 2), dim3(256), 0, stream>>>(Qb, Kb, Vtb, mask, yb);
  k_gemm<<<dim3(8, 32, 1), dim3(512), 0, stream>>>(
      yb, wpt, wpt, wpt, bp, bp, bp, 1.f, 1.f, 1.f,
      d_out, d_out, d_out, 2, 2, 2);
}